// Round 1
// baseline (284.019 us; speedup 1.0000x reference)
//
#include <hip/hip_runtime.h>
#include <hip/hip_bf16.h>

typedef float f32x4 __attribute__((ext_vector_type(4)));
typedef __bf16 bf16x8 __attribute__((ext_vector_type(8)));

static constexpr int S  = 2048;
static constexpr int D  = 1024;
static constexpr int DK = 64;
static constexpr int KDIM = 1024;

#define AS1 __attribute__((address_space(1)))
#define AS3 __attribute__((address_space(3)))

__device__ __forceinline__ void glds16(const void* g, void* l) {
  __builtin_amdgcn_global_load_lds((const AS1 void*)g, (AS3 void*)l, 16, 0, 0);
}

// ---------------- f32 -> bf16 conversion (vectorized, G13) ----------------
__global__ __launch_bounds__(256) void cvt4_kernel(const float* __restrict__ src,
                                                   __hip_bfloat16* __restrict__ dst,
                                                   int n4) {
  int i = blockIdx.x * 256 + threadIdx.x;
  if (i >= n4) return;
  float4 v = reinterpret_cast<const float4*>(src)[i];
  union { ushort4 u; __hip_bfloat16 h[4]; } o;
  o.h[0] = __float2bfloat16(v.x);
  o.h[1] = __float2bfloat16(v.y);
  o.h[2] = __float2bfloat16(v.z);
  o.h[3] = __float2bfloat16(v.w);
  reinterpret_cast<ushort4*>(dst)[i] = o.u;
}

// ---------------- RoPE tables (once per launch, fp32) ----------------
__global__ __launch_bounds__(256) void rope_tab_kernel(float* __restrict__ cosT,
                                                       float* __restrict__ sinT) {
  int idx = blockIdx.x * 256 + threadIdx.x;  // S * 32
  int s = idx >> 5, fi = idx & 31;
  float invf = powf(10000.0f, -(float)(2 * fi) / 64.0f);
  float ang = (float)s * invf;
  cosT[idx] = cosf(ang);
  sinT[idx] = sinf(ang);
}

// ---------------- m97-style 128x128x32 NT GEMM ----------------
// C[m,n] = sum_k A[m,k]*B[n,k].  MODE 1: QKV epilogue (RoPE on proj 0/1,
// scatter Q/K->(B,H,S,dk), V->(B,H,dk,S)).  MODE 0: plain f32 C.
template <int MODE>
__global__ __launch_bounds__(256) void gemm_nt_kernel(
    const __hip_bfloat16* __restrict__ A,
    const __hip_bfloat16* __restrict__ Bw,
    float* __restrict__ Cf,
    __hip_bfloat16* __restrict__ Qr,
    __hip_bfloat16* __restrict__ Kr,
    __hip_bfloat16* __restrict__ Vt,
    const float* __restrict__ cosT,
    const float* __restrict__ sinT,
    int Ncols) {
  __shared__ __attribute__((aligned(16))) __hip_bfloat16 Asm[128 * 32];
  __shared__ __attribute__((aligned(16))) __hip_bfloat16 Bsm[128 * 32];
  const int tid = threadIdx.x;
  const int nbn = Ncols >> 7;
  const int bm = blockIdx.x / nbn;
  const int bn = blockIdx.x % nbn;
  const int m0 = bm << 7, n0 = bn << 7;
  const int lane = tid & 63;
  const int wid = tid >> 6;
  const int wm = wid >> 1, wn = wid & 1;
  const int r16 = lane & 15, hf = lane >> 4;

  f32x4 acc[4][4];
#pragma unroll
  for (int i = 0; i < 4; ++i)
#pragma unroll
    for (int j = 0; j < 4; ++j) acc[i][j] = (f32x4)0.0f;

  for (int k0 = 0; k0 < KDIM; k0 += 32) {
    __syncthreads();
#pragma unroll
    for (int i = 0; i < 2; ++i) {
      const int idx = i * 256 + tid;
      const int row = idx >> 2;          // 128 rows x 4 16B-chunks
      const int cb = (idx & 3) << 4;
      glds16((const char*)A + ((size_t)(m0 + row) * KDIM + k0) * 2 + cb,
             (char*)Asm + idx * 16);
      glds16((const char*)Bw + ((size_t)(n0 + row) * KDIM + k0) * 2 + cb,
             (char*)Bsm + idx * 16);
    }
    __syncthreads();
    bf16x8 af[4], bfr[4];
#pragma unroll
    for (int mi = 0; mi < 4; ++mi)
      af[mi] = *(const bf16x8*)((const char*)Asm +
                                ((wm << 6) + (mi << 4) + r16) * 64 + hf * 16);
#pragma unroll
    for (int ni = 0; ni < 4; ++ni)
      bfr[ni] = *(const bf16x8*)((const char*)Bsm +
                                 ((wn << 6) + (ni << 4) + r16) * 64 + hf * 16);
#pragma unroll
    for (int mi = 0; mi < 4; ++mi)
#pragma unroll
      for (int ni = 0; ni < 4; ++ni)
        acc[mi][ni] = __builtin_amdgcn_mfma_f32_16x16x32_bf16(af[mi], bfr[ni],
                                                              acc[mi][ni], 0, 0, 0);
  }

  if constexpr (MODE == 0) {
#pragma unroll
    for (int mi = 0; mi < 4; ++mi) {
      const int rowb = m0 + (wm << 6) + (mi << 4) + (hf << 2);
#pragma unroll
      for (int ni = 0; ni < 4; ++ni) {
        const int col = n0 + (wn << 6) + (ni << 4) + r16;
#pragma unroll
        for (int r = 0; r < 4; ++r)
          Cf[(size_t)(rowb + r) * Ncols + col] = acc[mi][ni][r];
      }
    }
  } else {
    const int proj = n0 >> 10;  // block-uniform: 0=Q,1=K,2=V
#pragma unroll
    for (int mi = 0; mi < 4; ++mi) {
      const int rowb = m0 + (wm << 6) + (mi << 4) + (hf << 2);
#pragma unroll
      for (int ni = 0; ni < 4; ++ni) {
        const int col = n0 + (wn << 6) + (ni << 4) + r16;
        const int ecol = col & 1023;
        const int h = ecol >> 6, dk = ecol & 63;
#pragma unroll
        for (int r = 0; r < 4; ++r) {
          float v = acc[mi][ni][r];
          const int row = rowb + r;
          const int b = row >> 11, s = row & 2047;
          if (proj < 2) {
            // RoPE: even/odd dk pair lives in adjacent lanes (col=lane&15)
            float p = __shfl_xor(v, 1, 64);
            const int fi = dk >> 1;
            const float c = cosT[(s << 5) + fi];
            const float sn = sinT[(s << 5) + fi];
            const float ov = v * c + ((dk & 1) ? p : -p) * sn;
            __hip_bfloat16* dst = (proj == 0) ? Qr : Kr;
            dst[((size_t)((b << 4) + h) * S + s) * DK + dk] = __float2bfloat16(ov);
          } else {
            Vt[((size_t)((b << 4) + h) * DK + dk) * S + s] = __float2bfloat16(v);
          }
        }
      }
    }
  }
}

// ---------------- causal flash attention ----------------
// grid: bh(32) x qtile(32); 4 waves x 16 q-rows each; KV tiles of 64.
__global__ __launch_bounds__(256) void attn_kernel(
    const __hip_bfloat16* __restrict__ Q,   // (B,H,S,dk) post-RoPE
    const __hip_bfloat16* __restrict__ Kr,  // (B,H,S,dk) post-RoPE
    const __hip_bfloat16* __restrict__ Vt,  // (B,H,dk,S)
    __hip_bfloat16* __restrict__ AO) {      // (B,S,D)
  __shared__ __attribute__((aligned(16))) __hip_bfloat16 Ks[64 * 64];
  __shared__ __attribute__((aligned(16))) __hip_bfloat16 Vs[64 * 64];
  __shared__ __attribute__((aligned(16))) __hip_bfloat16 Ps[4][16 * 72];  // +16B pad
  const int tid = threadIdx.x;
  const int lane = tid & 63, wid = tid >> 6;
  const int r16 = lane & 15, hf = lane >> 4;
  const int qt = blockIdx.x & 31;
  const int bh = blockIdx.x >> 5;
  const __hip_bfloat16* Qh = Q + (size_t)bh * S * DK;
  const __hip_bfloat16* Kh = Kr + (size_t)bh * S * DK;
  const __hip_bfloat16* Vh = Vt + (size_t)bh * DK * S;

  // Q fragments, held in registers for the whole block
  const int qrow = (qt << 6) + (wid << 4) + r16;
  bf16x8 aq[2];
#pragma unroll
  for (int ks = 0; ks < 2; ++ks)
    aq[ks] = *(const bf16x8*)(Qh + (size_t)qrow * DK + ks * 32 + hf * 8);

  f32x4 o[4];
#pragma unroll
  for (int f = 0; f < 4; ++f) o[f] = (f32x4)0.0f;
  float m[4], l[4];
#pragma unroll
  for (int r = 0; r < 4; ++r) { m[r] = -1e30f; l[r] = 0.0f; }

  for (int kt = 0; kt <= qt; ++kt) {
    __syncthreads();
    // stage K (64x64) and V^T (64x64), XOR-swizzled via pre-swizzled source (rule #21)
#pragma unroll
    for (int i = 0; i < 2; ++i) {
      const int idx = i * 256 + tid;
      const int row = idx >> 3;           // 64 rows x 8 16B-chunks (128B rows)
      const int cb = (idx & 7) << 4;
      const int scb = cb ^ ((row & 7) << 4);
      glds16((const char*)Kh + ((size_t)((kt << 6) + row) * DK) * 2 + scb,
             (char*)Ks + idx * 16);
      glds16((const char*)Vh + ((size_t)row * S + (kt << 6)) * 2 + scb,
             (char*)Vs + idx * 16);
    }
    __syncthreads();

    // S = Q K^T
    f32x4 sa[4];
#pragma unroll
    for (int ni = 0; ni < 4; ++ni) sa[ni] = (f32x4)0.0f;
#pragma unroll
    for (int ks = 0; ks < 2; ++ks) {
#pragma unroll
      for (int ni = 0; ni < 4; ++ni) {
        const int krow = (ni << 4) + r16;
        const int cb = (ks << 6) + (hf << 4);
        const bf16x8 bk = *(const bf16x8*)((const char*)Ks + krow * 128 +
                                           (cb ^ ((krow & 7) << 4)));
        sa[ni] = __builtin_amdgcn_mfma_f32_16x16x32_bf16(aq[ks], bk, sa[ni], 0, 0, 0);
      }
    }

    // scale + causal mask
    float svv[4][4];
#pragma unroll
    for (int ni = 0; ni < 4; ++ni)
#pragma unroll
      for (int r = 0; r < 4; ++r) {
        float sv = sa[ni][r] * 0.125f;
        if (kt == qt) {
          const int kg = (kt << 6) + (ni << 4) + r16;
          const int qg = (qt << 6) + (wid << 4) + (hf << 2) + r;
          if (kg > qg) sv = -1e30f;
        }
        svv[ni][r] = sv;
      }

    // online softmax (wave-parallel butterflies over the 16-lane group)
    float scl[4];
#pragma unroll
    for (int r = 0; r < 4; ++r) {
      float v = fmaxf(fmaxf(svv[0][r], svv[1][r]), fmaxf(svv[2][r], svv[3][r]));
#pragma unroll
      for (int off = 1; off < 16; off <<= 1) v = fmaxf(v, __shfl_xor(v, off, 64));
      const float mn = fmaxf(m[r], v);
      scl[r] = __expf(m[r] - mn);
      m[r] = mn;
    }
    float rs[4] = {0.f, 0.f, 0.f, 0.f};
#pragma unroll
    for (int ni = 0; ni < 4; ++ni)
#pragma unroll
      for (int r = 0; r < 4; ++r) {
        const float p = __expf(svv[ni][r] - m[r]);
        rs[r] += p;
        Ps[wid][((hf << 2) + r) * 72 + (ni << 4) + r16] = __float2bfloat16(p);
      }
#pragma unroll
    for (int r = 0; r < 4; ++r) {
      float t = rs[r];
#pragma unroll
      for (int off = 1; off < 16; off <<= 1) t += __shfl_xor(t, off, 64);
      l[r] = l[r] * scl[r] + t;
#pragma unroll
      for (int f = 0; f < 4; ++f) o[f][r] *= scl[r];
    }

    // O += P V  (P redistributed via padded LDS; same-wave, no barrier needed)
#pragma unroll
    for (int ks = 0; ks < 2; ++ks) {
      const bf16x8 pa = *(const bf16x8*)((const char*)&Ps[wid][0] + r16 * 144 +
                                         (ks << 6) + (hf << 4));
#pragma unroll
      for (int f = 0; f < 4; ++f) {
        const int vrow = (f << 4) + r16;
        const int cb = (ks << 6) + (hf << 4);
        const bf16x8 bv = *(const bf16x8*)((const char*)Vs + vrow * 128 +
                                           (cb ^ ((vrow & 7) << 4)));
        o[f] = __builtin_amdgcn_mfma_f32_16x16x32_bf16(pa, bv, o[f], 0, 0, 0);
      }
    }
  }

  // normalize + write attn_out (B,S,D) in bf16
  const int b = bh >> 4, h = bh & 15;
#pragma unroll
  for (int r = 0; r < 4; ++r) {
    const float inv = 1.0f / l[r];
    const int q = (qt << 6) + (wid << 4) + (hf << 2) + r;
#pragma unroll
    for (int f = 0; f < 4; ++f)
      AO[((size_t)b * S + q) * D + (h << 6) + (f << 4) + r16] =
          __float2bfloat16(o[f][r] * inv);
  }
}

extern "C" void kernel_launch(void* const* d_in, const int* in_sizes, int n_in,
                              void* d_out, int out_size, void* d_ws, size_t ws_size,
                              hipStream_t stream) {
  (void)in_sizes; (void)n_in; (void)out_size; (void)ws_size;
  const float* x  = (const float*)d_in[0];
  const float* Wq = (const float*)d_in[1];
  const float* Wk = (const float*)d_in[2];
  const float* Wv = (const float*)d_in[3];
  const float* Wo = (const float*)d_in[4];
  float* out = (float*)d_out;
  char* ws = (char*)d_ws;
  const size_t MB = (size_t)1 << 20;
  __hip_bfloat16* xb   = (__hip_bfloat16*)(ws);             //  8 MB (4096x1024)
  __hip_bfloat16* Wcat = (__hip_bfloat16*)(ws + 8 * MB);    //  6 MB (3072x1024)
  __hip_bfloat16* Wob  = (__hip_bfloat16*)(ws + 14 * MB);   //  2 MB
  __hip_bfloat16* Qr   = (__hip_bfloat16*)(ws + 16 * MB);   //  8 MB (B,H,S,dk)
  __hip_bfloat16* Kr   = (__hip_bfloat16*)(ws + 24 * MB);   //  8 MB
  __hip_bfloat16* Vt   = (__hip_bfloat16*)(ws + 32 * MB);   //  8 MB (B,H,dk,S)
  __hip_bfloat16* AO   = (__hip_bfloat16*)(ws + 40 * MB);   //  8 MB (B,S,D)
  float* cosT = (float*)(ws + 48 * MB);                     // 256 KB
  float* sinT = (float*)(ws + 48 * MB + 256 * 1024);        // 256 KB

  cvt4_kernel<<<4096, 256, 0, stream>>>(x, xb, (2 * 2048 * 1024) / 4);
  cvt4_kernel<<<1024, 256, 0, stream>>>(Wq, Wcat, (1024 * 1024) / 4);
  cvt4_kernel<<<1024, 256, 0, stream>>>(Wk, Wcat + 1024 * 1024, (1024 * 1024) / 4);
  cvt4_kernel<<<1024, 256, 0, stream>>>(Wv, Wcat + 2 * 1024 * 1024, (1024 * 1024) / 4);
  cvt4_kernel<<<1024, 256, 0, stream>>>(Wo, Wob, (1024 * 1024) / 4);
  rope_tab_kernel<<<(2048 * 32) / 256, 256, 0, stream>>>(cosT, sinT);

  // fused QKV projection + RoPE + scatter
  gemm_nt_kernel<1><<<(4096 / 128) * (3072 / 128), 256, 0, stream>>>(
      xb, Wcat, nullptr, Qr, Kr, Vt, cosT, sinT, 3072);
  // causal flash attention
  attn_kernel<<<32 * (2048 / 64), 256, 0, stream>>>(Qr, Kr, Vt, AO);
  // output projection (f32 out)
  gemm_nt_kernel<0><<<(4096 / 128) * (1024 / 128), 256, 0, stream>>>(
      AO, Wob, out, nullptr, nullptr, nullptr, nullptr, nullptr, 1024);
}

// Round 2
// 257.402 us; speedup vs baseline: 1.1034x; 1.1034x over previous
//
#include <hip/hip_runtime.h>
#include <hip/hip_bf16.h>

typedef float f32x4 __attribute__((ext_vector_type(4)));
typedef __bf16 bf16x8 __attribute__((ext_vector_type(8)));

static constexpr int S  = 2048;
static constexpr int D  = 1024;
static constexpr int DK = 64;
static constexpr int KDIM = 1024;

#define AS1 __attribute__((address_space(1)))
#define AS3 __attribute__((address_space(3)))

__device__ __forceinline__ void glds16(const void* g, void* l) {
  __builtin_amdgcn_global_load_lds((const AS1 void*)g, (AS3 void*)l, 16, 0, 0);
}

// ---------------- f32 -> bf16 conversion (vectorized, G13) ----------------
__global__ __launch_bounds__(256) void cvt4_kernel(const float* __restrict__ src,
                                                   __hip_bfloat16* __restrict__ dst,
                                                   int n4) {
  int i = blockIdx.x * 256 + threadIdx.x;
  if (i >= n4) return;
  float4 v = reinterpret_cast<const float4*>(src)[i];
  union { ushort4 u; __hip_bfloat16 h[4]; } o;
  o.h[0] = __float2bfloat16(v.x);
  o.h[1] = __float2bfloat16(v.y);
  o.h[2] = __float2bfloat16(v.z);
  o.h[3] = __float2bfloat16(v.w);
  reinterpret_cast<ushort4*>(dst)[i] = o.u;
}

// ---------------- RoPE tables (once per launch, fp32) ----------------
__global__ __launch_bounds__(256) void rope_tab_kernel(float* __restrict__ cosT,
                                                       float* __restrict__ sinT) {
  int idx = blockIdx.x * 256 + threadIdx.x;  // S * 32
  int s = idx >> 5, fi = idx & 31;
  float invf = powf(10000.0f, -(float)(2 * fi) / 64.0f);
  float ang = (float)s * invf;
  cosT[idx] = cosf(ang);
  sinT[idx] = sinf(ang);
}

// ---------------- m97-style 128x128x32 NT GEMM ----------------
template <int MODE>
__global__ __launch_bounds__(256) void gemm_nt_kernel(
    const __hip_bfloat16* __restrict__ A,
    const __hip_bfloat16* __restrict__ Bw,
    float* __restrict__ Cf,
    __hip_bfloat16* __restrict__ Qr,
    __hip_bfloat16* __restrict__ Kr,
    __hip_bfloat16* __restrict__ Vt,
    const float* __restrict__ cosT,
    const float* __restrict__ sinT,
    int Ncols) {
  __shared__ __attribute__((aligned(16))) __hip_bfloat16 Asm[128 * 32];
  __shared__ __attribute__((aligned(16))) __hip_bfloat16 Bsm[128 * 32];
  const int tid = threadIdx.x;
  const int nbn = Ncols >> 7;
  const int bm = blockIdx.x / nbn;
  const int bn = blockIdx.x % nbn;
  const int m0 = bm << 7, n0 = bn << 7;
  const int lane = tid & 63;
  const int wid = tid >> 6;
  const int wm = wid >> 1, wn = wid & 1;
  const int r16 = lane & 15, hf = lane >> 4;

  f32x4 acc[4][4];
#pragma unroll
  for (int i = 0; i < 4; ++i)
#pragma unroll
    for (int j = 0; j < 4; ++j) acc[i][j] = (f32x4)0.0f;

  for (int k0 = 0; k0 < KDIM; k0 += 32) {
    __syncthreads();
#pragma unroll
    for (int i = 0; i < 2; ++i) {
      const int idx = i * 256 + tid;
      const int row = idx >> 2;
      const int cb = (idx & 3) << 4;
      glds16((const char*)A + ((size_t)(m0 + row) * KDIM + k0) * 2 + cb,
             (char*)Asm + idx * 16);
      glds16((const char*)Bw + ((size_t)(n0 + row) * KDIM + k0) * 2 + cb,
             (char*)Bsm + idx * 16);
    }
    __syncthreads();
    bf16x8 af[4], bfr[4];
#pragma unroll
    for (int mi = 0; mi < 4; ++mi)
      af[mi] = *(const bf16x8*)((const char*)Asm +
                                ((wm << 6) + (mi << 4) + r16) * 64 + hf * 16);
#pragma unroll
    for (int ni = 0; ni < 4; ++ni)
      bfr[ni] = *(const bf16x8*)((const char*)Bsm +
                                 ((wn << 6) + (ni << 4) + r16) * 64 + hf * 16);
#pragma unroll
    for (int mi = 0; mi < 4; ++mi)
#pragma unroll
      for (int ni = 0; ni < 4; ++ni)
        acc[mi][ni] = __builtin_amdgcn_mfma_f32_16x16x32_bf16(af[mi], bfr[ni],
                                                              acc[mi][ni], 0, 0, 0);
  }

  if constexpr (MODE == 0) {
#pragma unroll
    for (int mi = 0; mi < 4; ++mi) {
      const int rowb = m0 + (wm << 6) + (mi << 4) + (hf << 2);
#pragma unroll
      for (int ni = 0; ni < 4; ++ni) {
        const int col = n0 + (wn << 6) + (ni << 4) + r16;
#pragma unroll
        for (int r = 0; r < 4; ++r)
          Cf[(size_t)(rowb + r) * Ncols + col] = acc[mi][ni][r];
      }
    }
  } else {
    const int proj = n0 >> 10;
#pragma unroll
    for (int mi = 0; mi < 4; ++mi) {
      const int rowb = m0 + (wm << 6) + (mi << 4) + (hf << 2);
#pragma unroll
      for (int ni = 0; ni < 4; ++ni) {
        const int col = n0 + (wn << 6) + (ni << 4) + r16;
        const int ecol = col & 1023;
        const int h = ecol >> 6, dk = ecol & 63;
#pragma unroll
        for (int r = 0; r < 4; ++r) {
          float v = acc[mi][ni][r];
          const int row = rowb + r;
          const int b = row >> 11, s = row & 2047;
          if (proj < 2) {
            float p = __shfl_xor(v, 1, 64);
            const int fi = dk >> 1;
            const float c = cosT[(s << 5) + fi];
            const float sn = sinT[(s << 5) + fi];
            const float ov = v * c + ((dk & 1) ? p : -p) * sn;
            __hip_bfloat16* dst = (proj == 0) ? Qr : Kr;
            dst[((size_t)((b << 4) + h) * S + s) * DK + dk] = __float2bfloat16(ov);
          } else {
            Vt[((size_t)((b << 4) + h) * DK + dk) * S + s] = __float2bfloat16(v);
          }
        }
      }
    }
  }
}

// ---------------- causal flash attention v2 ----------------
// QBLK=128 (4 waves x 32 q-rows, 2 m-frags), KVBLK=64, double-buffered K/V
// staging with stage-before-compute (T3 minimum 2-phase), single barrier/iter.
__global__ __launch_bounds__(256) void attn_kernel(
    const __hip_bfloat16* __restrict__ Q,   // (B,H,S,dk) post-RoPE
    const __hip_bfloat16* __restrict__ Kr,  // (B,H,S,dk) post-RoPE
    const __hip_bfloat16* __restrict__ Vt,  // (B,H,dk,S)
    __hip_bfloat16* __restrict__ AO) {      // (B,S,D)
  __shared__ __attribute__((aligned(16))) __hip_bfloat16 Ks[2][64 * 64];
  __shared__ __attribute__((aligned(16))) __hip_bfloat16 Vs[2][64 * 64];
  __shared__ __attribute__((aligned(16))) __hip_bfloat16 Ps[4][32 * 72];  // +16B pad
  const int tid = threadIdx.x;
  const int lane = tid & 63, wid = tid >> 6;
  const int r16 = lane & 15, hf = lane >> 4;
  const int qt = 15 - (blockIdx.x >> 5);  // descending work: long blocks first
  const int bh = blockIdx.x & 31;
  const __hip_bfloat16* Qh = Q + (size_t)bh * S * DK;
  const __hip_bfloat16* Kh = Kr + (size_t)bh * S * DK;
  const __hip_bfloat16* Vh = Vt + (size_t)bh * DK * S;

  // Q fragments in registers: 2 m-frags x 2 k-slices
  bf16x8 aq[2][2];
#pragma unroll
  for (int mi = 0; mi < 2; ++mi)
#pragma unroll
    for (int ks = 0; ks < 2; ++ks)
      aq[mi][ks] = *(const bf16x8*)(Qh +
          (size_t)((qt << 7) + (mi << 6) + (wid << 4) + r16) * DK + ks * 32 + hf * 8);

  f32x4 o[2][4];
  float m[2][4], l[2][4];
#pragma unroll
  for (int mi = 0; mi < 2; ++mi)
#pragma unroll
    for (int f = 0; f < 4; ++f) o[mi][f] = (f32x4)0.0f;
#pragma unroll
  for (int mi = 0; mi < 2; ++mi)
#pragma unroll
    for (int r = 0; r < 4; ++r) { m[mi][r] = -1e30f; l[mi][r] = 0.0f; }

  const int nt = (qt << 1) + 2;  // KV tiles covering causal extent

#define STAGE(bufi, t)                                                         \
  {                                                                            \
    _Pragma("unroll") for (int i = 0; i < 2; ++i) {                            \
      const int idx = i * 256 + tid;                                           \
      const int row = idx >> 3;                                                \
      const int cb = (idx & 7) << 4;                                           \
      const int scb = cb ^ ((row & 7) << 4);                                   \
      glds16((const char*)Kh + ((size_t)(((t) << 6) + row) * DK) * 2 + scb,    \
             (char*)Ks[bufi] + idx * 16);                                      \
      glds16((const char*)Vh + ((size_t)row * S + ((t) << 6)) * 2 + scb,       \
             (char*)Vs[bufi] + idx * 16);                                      \
    }                                                                          \
  }

  STAGE(0, 0);
  __syncthreads();

  for (int kt = 0; kt < nt; ++kt) {
    const int cur = kt & 1;
    if (kt + 1 < nt) STAGE(cur ^ 1, kt + 1);

    // S = Q K^T  (16 MFMA; K-frag shared across m-frags)
    f32x4 sa[2][4];
#pragma unroll
    for (int mi = 0; mi < 2; ++mi)
#pragma unroll
      for (int ni = 0; ni < 4; ++ni) sa[mi][ni] = (f32x4)0.0f;
#pragma unroll
    for (int ks = 0; ks < 2; ++ks) {
#pragma unroll
      for (int ni = 0; ni < 4; ++ni) {
        const int krow = (ni << 4) + r16;
        const int cb = (ks << 6) + (hf << 4);
        const bf16x8 bk = *(const bf16x8*)((const char*)Ks[cur] + krow * 128 +
                                           (cb ^ ((krow & 7) << 4)));
#pragma unroll
        for (int mi = 0; mi < 2; ++mi)
          sa[mi][ni] = __builtin_amdgcn_mfma_f32_16x16x32_bf16(aq[mi][ks], bk,
                                                               sa[mi][ni], 0, 0, 0);
      }
    }

    // scale + causal mask (wave-uniform skip for interior tiles)
    float svv[2][4][4];
    const bool diag = (kt >= (qt << 1));
#pragma unroll
    for (int mi = 0; mi < 2; ++mi)
#pragma unroll
      for (int ni = 0; ni < 4; ++ni)
#pragma unroll
        for (int r = 0; r < 4; ++r) {
          float sv = sa[mi][ni][r] * 0.125f;
          if (diag) {
            const int kg = (kt << 6) + (ni << 4) + r16;
            const int qg = (qt << 7) + (mi << 6) + (wid << 4) + (hf << 2) + r;
            if (kg > qg) sv = -1e30f;
          }
          svv[mi][ni][r] = sv;
        }

    // online softmax (wave-parallel 16-lane butterflies)
    float scl[2][4];
#pragma unroll
    for (int mi = 0; mi < 2; ++mi)
#pragma unroll
      for (int r = 0; r < 4; ++r) {
        float v = fmaxf(fmaxf(svv[mi][0][r], svv[mi][1][r]),
                        fmaxf(svv[mi][2][r], svv[mi][3][r]));
#pragma unroll
        for (int off = 1; off < 16; off <<= 1) v = fmaxf(v, __shfl_xor(v, off, 64));
        const float mn = fmaxf(m[mi][r], v);
        scl[mi][r] = __expf(m[mi][r] - mn);
        m[mi][r] = mn;
      }
    float rs[2][4];
#pragma unroll
    for (int mi = 0; mi < 2; ++mi)
#pragma unroll
      for (int r = 0; r < 4; ++r) rs[mi][r] = 0.0f;
#pragma unroll
    for (int mi = 0; mi < 2; ++mi)
#pragma unroll
      for (int ni = 0; ni < 4; ++ni)
#pragma unroll
        for (int r = 0; r < 4; ++r) {
          const float p = __expf(svv[mi][ni][r] - m[mi][r]);
          rs[mi][r] += p;
          Ps[wid][((mi << 4) + (hf << 2) + r) * 72 + (ni << 4) + r16] =
              __float2bfloat16(p);
        }
#pragma unroll
    for (int mi = 0; mi < 2; ++mi)
#pragma unroll
      for (int r = 0; r < 4; ++r) {
        float t = rs[mi][r];
#pragma unroll
        for (int off = 1; off < 16; off <<= 1) t += __shfl_xor(t, off, 64);
        l[mi][r] = l[mi][r] * scl[mi][r] + t;
#pragma unroll
        for (int f = 0; f < 4; ++f) o[mi][f][r] *= scl[mi][r];
      }

    // O += P V  (16 MFMA; V-frag shared across m-frags)
#pragma unroll
    for (int ks = 0; ks < 2; ++ks) {
      bf16x8 pa[2];
#pragma unroll
      for (int mi = 0; mi < 2; ++mi)
        pa[mi] = *(const bf16x8*)((const char*)&Ps[wid][0] +
                                  ((mi << 4) + r16) * 144 + (ks << 6) + (hf << 4));
#pragma unroll
      for (int f = 0; f < 4; ++f) {
        const int vrow = (f << 4) + r16;
        const int cb = (ks << 6) + (hf << 4);
        const bf16x8 bv = *(const bf16x8*)((const char*)Vs[cur] + vrow * 128 +
                                           (cb ^ ((vrow & 7) << 4)));
#pragma unroll
        for (int mi = 0; mi < 2; ++mi)
          o[mi][f] = __builtin_amdgcn_mfma_f32_16x16x32_bf16(pa[mi], bv,
                                                             o[mi][f], 0, 0, 0);
      }
    }

    __syncthreads();  // drains this iter's prefetch (issued before compute)
  }
#undef STAGE

  // normalize + write attn_out (B,S,D) in bf16
  const int b = bh >> 4, h = bh & 15;
#pragma unroll
  for (int mi = 0; mi < 2; ++mi)
#pragma unroll
    for (int r = 0; r < 4; ++r) {
      const float inv = 1.0f / l[mi][r];
      const int q = (qt << 7) + (mi << 6) + (wid << 4) + (hf << 2) + r;
#pragma unroll
      for (int f = 0; f < 4; ++f)
        AO[((size_t)b * S + q) * D + (h << 6) + (f << 4) + r16] =
            __float2bfloat16(o[mi][f][r] * inv);
    }
}

extern "C" void kernel_launch(void* const* d_in, const int* in_sizes, int n_in,
                              void* d_out, int out_size, void* d_ws, size_t ws_size,
                              hipStream_t stream) {
  (void)in_sizes; (void)n_in; (void)out_size; (void)ws_size;
  const float* x  = (const float*)d_in[0];
  const float* Wq = (const float*)d_in[1];
  const float* Wk = (const float*)d_in[2];
  const float* Wv = (const float*)d_in[3];
  const float* Wo = (const float*)d_in[4];
  float* out = (float*)d_out;
  char* ws = (char*)d_ws;
  const size_t MB = (size_t)1 << 20;
  __hip_bfloat16* xb   = (__hip_bfloat16*)(ws);             //  8 MB
  __hip_bfloat16* Wcat = (__hip_bfloat16*)(ws + 8 * MB);    //  6 MB
  __hip_bfloat16* Wob  = (__hip_bfloat16*)(ws + 14 * MB);   //  2 MB
  __hip_bfloat16* Qr   = (__hip_bfloat16*)(ws + 16 * MB);   //  8 MB (B,H,S,dk)
  __hip_bfloat16* Kr   = (__hip_bfloat16*)(ws + 24 * MB);   //  8 MB
  __hip_bfloat16* Vt   = (__hip_bfloat16*)(ws + 32 * MB);   //  8 MB (B,H,dk,S)
  __hip_bfloat16* AO   = (__hip_bfloat16*)(ws + 40 * MB);   //  8 MB (B,S,D)
  float* cosT = (float*)(ws + 48 * MB);                     // 256 KB
  float* sinT = (float*)(ws + 48 * MB + 256 * 1024);        // 256 KB

  cvt4_kernel<<<4096, 256, 0, stream>>>(x, xb, (2 * 2048 * 1024) / 4);
  cvt4_kernel<<<1024, 256, 0, stream>>>(Wq, Wcat, (1024 * 1024) / 4);
  cvt4_kernel<<<1024, 256, 0, stream>>>(Wk, Wcat + 1024 * 1024, (1024 * 1024) / 4);
  cvt4_kernel<<<1024, 256, 0, stream>>>(Wv, Wcat + 2 * 1024 * 1024, (1024 * 1024) / 4);
  cvt4_kernel<<<1024, 256, 0, stream>>>(Wo, Wob, (1024 * 1024) / 4);
  rope_tab_kernel<<<(2048 * 32) / 256, 256, 0, stream>>>(cosT, sinT);

  gemm_nt_kernel<1><<<(4096 / 128) * (3072 / 128), 256, 0, stream>>>(
      xb, Wcat, nullptr, Qr, Kr, Vt, cosT, sinT, 3072);
  attn_kernel<<<32 * 16, 256, 0, stream>>>(Qr, Kr, Vt, AO);
  gemm_nt_kernel<0><<<(4096 / 128) * (1024 / 128), 256, 0, stream>>>(
      AO, Wob, out, nullptr, nullptr, nullptr, nullptr, nullptr, 1024);
}

// Round 3
// 230.641 us; speedup vs baseline: 1.2314x; 1.1160x over previous
//
#include <hip/hip_runtime.h>
#include <hip/hip_bf16.h>

typedef float f32x4 __attribute__((ext_vector_type(4)));
typedef __bf16 bf16x8 __attribute__((ext_vector_type(8)));

static constexpr int S  = 2048;
static constexpr int D  = 1024;
static constexpr int DK = 64;
static constexpr int KDIM = 1024;

#define AS1 __attribute__((address_space(1)))
#define AS3 __attribute__((address_space(3)))

__device__ __forceinline__ void glds16(const void* g, void* l) {
  __builtin_amdgcn_global_load_lds((const AS1 void*)g, (AS3 void*)l, 16, 0, 0);
}

__device__ __forceinline__ unsigned cvtpk(float lo, float hi) {
  unsigned r;
  asm("v_cvt_pk_bf16_f32 %0, %1, %2" : "=v"(r) : "v"(lo), "v"(hi));
  return r;
}

// swap upper-32-lanes of a with lower-32-lanes of b (gfx950)
__device__ __forceinline__ void pl32swap(unsigned& a, unsigned& b) {
  asm("v_permlane32_swap_b32 %0, %1" : "+v"(a), "+v"(b));
}

// k-permutation within a 64 block: source k -> virtual k' consumed by the
// in-register P-transform (see attn_kernel). Bijective.
__device__ __forceinline__ int kperm64(int k) {
  const int kf = k >> 4, hs = (k >> 2) & 3, r = k & 3;
  const bool inl = ((kf & 1) == (hs >> 1));
  const int h = inl ? hs : (hs ^ 2);
  const int j = inl ? r : (r + 4);
  return ((kf >> 1) << 5) + (h << 3) + j;
}

// ---------------- f32 -> bf16 conversion (vectorized, G13) ----------------
__global__ __launch_bounds__(256) void cvt4_kernel(const float* __restrict__ src,
                                                   __hip_bfloat16* __restrict__ dst,
                                                   int n4) {
  int i = blockIdx.x * 256 + threadIdx.x;
  if (i >= n4) return;
  float4 v = reinterpret_cast<const float4*>(src)[i];
  union { ushort4 u; __hip_bfloat16 h[4]; } o;
  o.h[0] = __float2bfloat16(v.x);
  o.h[1] = __float2bfloat16(v.y);
  o.h[2] = __float2bfloat16(v.z);
  o.h[3] = __float2bfloat16(v.w);
  reinterpret_cast<ushort4*>(dst)[i] = o.u;
}

// ---------------- RoPE tables (once per launch, fp32) ----------------
__global__ __launch_bounds__(256) void rope_tab_kernel(float* __restrict__ cosT,
                                                       float* __restrict__ sinT) {
  int idx = blockIdx.x * 256 + threadIdx.x;  // S * 32
  int s = idx >> 5, fi = idx & 31;
  float invf = powf(10000.0f, -(float)(2 * fi) / 64.0f);
  float ang = (float)s * invf;
  cosT[idx] = cosf(ang);
  sinT[idx] = sinf(ang);
}

// ---------------- m97-style 128x128x32 NT GEMM ----------------
template <int MODE>
__global__ __launch_bounds__(256) void gemm_nt_kernel(
    const __hip_bfloat16* __restrict__ A,
    const __hip_bfloat16* __restrict__ Bw,
    float* __restrict__ Cf,
    __hip_bfloat16* __restrict__ Qr,
    __hip_bfloat16* __restrict__ Kr,
    __hip_bfloat16* __restrict__ Vt,
    const float* __restrict__ cosT,
    const float* __restrict__ sinT,
    int Ncols) {
  __shared__ __attribute__((aligned(16))) __hip_bfloat16 Asm[128 * 32];
  __shared__ __attribute__((aligned(16))) __hip_bfloat16 Bsm[128 * 32];
  const int tid = threadIdx.x;
  const int nbn = Ncols >> 7;
  const int bm = blockIdx.x / nbn;
  const int bn = blockIdx.x % nbn;
  const int m0 = bm << 7, n0 = bn << 7;
  const int lane = tid & 63;
  const int wid = tid >> 6;
  const int wm = wid >> 1, wn = wid & 1;
  const int r16 = lane & 15, hf = lane >> 4;

  f32x4 acc[4][4];
#pragma unroll
  for (int i = 0; i < 4; ++i)
#pragma unroll
    for (int j = 0; j < 4; ++j) acc[i][j] = (f32x4)0.0f;

  for (int k0 = 0; k0 < KDIM; k0 += 32) {
    __syncthreads();
#pragma unroll
    for (int i = 0; i < 2; ++i) {
      const int idx = i * 256 + tid;
      const int row = idx >> 2;
      const int cb = (idx & 3) << 4;
      glds16((const char*)A + ((size_t)(m0 + row) * KDIM + k0) * 2 + cb,
             (char*)Asm + idx * 16);
      glds16((const char*)Bw + ((size_t)(n0 + row) * KDIM + k0) * 2 + cb,
             (char*)Bsm + idx * 16);
    }
    __syncthreads();
    bf16x8 af[4], bfr[4];
#pragma unroll
    for (int mi = 0; mi < 4; ++mi)
      af[mi] = *(const bf16x8*)((const char*)Asm +
                                ((wm << 6) + (mi << 4) + r16) * 64 + hf * 16);
#pragma unroll
    for (int ni = 0; ni < 4; ++ni)
      bfr[ni] = *(const bf16x8*)((const char*)Bsm +
                                 ((wn << 6) + (ni << 4) + r16) * 64 + hf * 16);
#pragma unroll
    for (int mi = 0; mi < 4; ++mi)
#pragma unroll
      for (int ni = 0; ni < 4; ++ni)
        acc[mi][ni] = __builtin_amdgcn_mfma_f32_16x16x32_bf16(af[mi], bfr[ni],
                                                              acc[mi][ni], 0, 0, 0);
  }

  if constexpr (MODE == 0) {
#pragma unroll
    for (int mi = 0; mi < 4; ++mi) {
      const int rowb = m0 + (wm << 6) + (mi << 4) + (hf << 2);
#pragma unroll
      for (int ni = 0; ni < 4; ++ni) {
        const int col = n0 + (wn << 6) + (ni << 4) + r16;
#pragma unroll
        for (int r = 0; r < 4; ++r)
          Cf[(size_t)(rowb + r) * Ncols + col] = acc[mi][ni][r];
      }
    }
  } else {
    const int proj = n0 >> 10;
#pragma unroll
    for (int mi = 0; mi < 4; ++mi) {
      const int rowb = m0 + (wm << 6) + (mi << 4) + (hf << 2);
#pragma unroll
      for (int ni = 0; ni < 4; ++ni) {
        const int col = n0 + (wn << 6) + (ni << 4) + r16;
        const int ecol = col & 1023;
        const int h = ecol >> 6, dk = ecol & 63;
#pragma unroll
        for (int r = 0; r < 4; ++r) {
          float v = acc[mi][ni][r];
          const int row = rowb + r;
          const int b = row >> 11, s = row & 2047;
          if (proj < 2) {
            float p = __shfl_xor(v, 1, 64);
            const int fi = dk >> 1;
            const float c = cosT[(s << 5) + fi];
            const float sn = sinT[(s << 5) + fi];
            const float ov = v * c + ((dk & 1) ? p : -p) * sn;
            __hip_bfloat16* dst = (proj == 0) ? Qr : Kr;
            dst[((size_t)((b << 4) + h) * S + s) * DK + dk] = __float2bfloat16(ov);
          } else {
            // V: permute k within each 64-block so the attention kernel's
            // in-register P-transform lines up (PV k-sum is order-agnostic).
            const int sp = (s & ~63) | kperm64(s & 63);
            Vt[((size_t)((b << 4) + h) * DK + dk) * S + sp] = __float2bfloat16(v);
          }
        }
      }
    }
  }
}

// ---------------- causal flash attention v3 (swapped-operand softmax) ------
// QBLK=128 (4 waves x 32 q), KVBLK=64, dbuf K/V. QK^T computed as mfma(K,Q)
// so each lane holds 16 P-values of ONE q-row -> row reduce is in-register +
// 2 shfl. P->bf16 via v_cvt_pk + permlane32_swap (zero LDS ops). PV computes
// O^T = mfma(V', P) with V k-permuted at write time (kperm64).
__global__ __launch_bounds__(256) void attn_kernel(
    const __hip_bfloat16* __restrict__ Q,   // (B,H,S,dk) post-RoPE
    const __hip_bfloat16* __restrict__ Kr,  // (B,H,S,dk) post-RoPE
    const __hip_bfloat16* __restrict__ Vp,  // (B,H,dk,S) k-permuted per 64
    __hip_bfloat16* __restrict__ AO) {      // (B,S,D)
  __shared__ __attribute__((aligned(16))) __hip_bfloat16 Ks[2][64 * 64];
  __shared__ __attribute__((aligned(16))) __hip_bfloat16 Vs[2][64 * 64];
  const int tid = threadIdx.x;
  const int lane = tid & 63, wid = tid >> 6;
  const int r16 = lane & 15, hf = lane >> 4;
  const bool hi32 = (lane >= 32);
  const int qt = 15 - (blockIdx.x >> 5);  // long blocks first
  const int bh = blockIdx.x & 31;
  const __hip_bfloat16* Qh = Q + (size_t)bh * S * DK;
  const __hip_bfloat16* Kh = Kr + (size_t)bh * S * DK;
  const __hip_bfloat16* Vh = Vp + (size_t)bh * DK * S;

  const int qbase = (qt << 7) + (wid << 5);  // wave's 32 q-rows

  // Q as MFMA B-operand fragments (col=q): bq[qf][ks]
  bf16x8 bq[2][2];
#pragma unroll
  for (int qf = 0; qf < 2; ++qf)
#pragma unroll
    for (int ks = 0; ks < 2; ++ks)
      bq[qf][ks] = *(const bf16x8*)(Qh + (size_t)(qbase + (qf << 4) + r16) * DK +
                                    ks * 32 + hf * 8);

  f32x4 o[2][4];  // O^T frags: [qf][dv-frag]; lane: dv=f*16+hf*4+r, q=qf*16+r16
#pragma unroll
  for (int qf = 0; qf < 2; ++qf)
#pragma unroll
    for (int f = 0; f < 4; ++f) o[qf][f] = (f32x4)0.0f;
  float m[2] = {-1e30f, -1e30f}, l[2] = {0.0f, 0.0f};

  const int nt = (qt << 1) + 2;

#define STAGE(bufi, t)                                                         \
  {                                                                            \
    _Pragma("unroll") for (int i = 0; i < 2; ++i) {                            \
      const int idx = i * 256 + tid;                                           \
      const int row = idx >> 3;                                                \
      const int cb = (idx & 7) << 4;                                           \
      const int scb = cb ^ ((row & 7) << 4);                                   \
      glds16((const char*)Kh + ((size_t)(((t) << 6) + row) * DK) * 2 + scb,    \
             (char*)(&Ks[bufi][0]) + idx * 16);                                \
      glds16((const char*)Vh + ((size_t)row * S + ((t) << 6)) * 2 + scb,       \
             (char*)(&Vs[bufi][0]) + idx * 16);                                \
    }                                                                          \
  }

  STAGE(0, 0);
  __syncthreads();

  for (int kt = 0; kt < nt; ++kt) {
    const int cur = kt & 1;
    if (kt + 1 < nt) STAGE(cur ^ 1, kt + 1);

    // ---- S^T = K Q^T : p[qf][kf][r] = P[k=kf*16+hf*4+r][q=qf*16+r16] ----
    f32x4 p[2][4];
#pragma unroll
    for (int qf = 0; qf < 2; ++qf)
#pragma unroll
      for (int kf = 0; kf < 4; ++kf) p[qf][kf] = (f32x4)0.0f;
    __builtin_amdgcn_s_setprio(1);
#pragma unroll
    for (int ks = 0; ks < 2; ++ks) {
#pragma unroll
      for (int kf = 0; kf < 4; ++kf) {
        const int krow = (kf << 4) + r16;
        const int cb = (ks << 6) + (hf << 4);
        const bf16x8 ak = *(const bf16x8*)((const char*)(&Ks[cur][0]) +
                                           krow * 128 + (cb ^ ((krow & 7) << 4)));
#pragma unroll
        for (int qf = 0; qf < 2; ++qf)
          p[qf][kf] = __builtin_amdgcn_mfma_f32_16x16x32_bf16(ak, bq[qf][ks],
                                                              p[qf][kf], 0, 0, 0);
      }
    }
    __builtin_amdgcn_s_setprio(0);

    // ---- scale + causal mask ----
    const bool diag = (kt >= (qt << 1));
#pragma unroll
    for (int qf = 0; qf < 2; ++qf) {
      const int qg = qbase + (qf << 4) + r16;
#pragma unroll
      for (int kf = 0; kf < 4; ++kf)
#pragma unroll
        for (int r = 0; r < 4; ++r) {
          float sv = p[qf][kf][r] * 0.125f;
          if (diag) {
            const int kg = (kt << 6) + (kf << 4) + (hf << 2) + r;
            if (kg > qg) sv = -1e30f;
          }
          p[qf][kf][r] = sv;
        }
    }

    // ---- online softmax: per-lane row (16 vals) + 2 shfl ----
    float scl[2];
#pragma unroll
    for (int qf = 0; qf < 2; ++qf) {
      float t = p[qf][0][0];
#pragma unroll
      for (int kf = 0; kf < 4; ++kf)
#pragma unroll
        for (int r = 0; r < 4; ++r) t = fmaxf(t, p[qf][kf][r]);
      t = fmaxf(t, __shfl_xor(t, 16, 64));
      t = fmaxf(t, __shfl_xor(t, 32, 64));
      const float mn = fmaxf(m[qf], t);
      scl[qf] = __expf(m[qf] - mn);
      m[qf] = mn;
      float ss = 0.0f;
#pragma unroll
      for (int kf = 0; kf < 4; ++kf)
#pragma unroll
        for (int r = 0; r < 4; ++r) {
          const float e = __expf(p[qf][kf][r] - mn);
          p[qf][kf][r] = e;
          ss += e;
        }
      ss += __shfl_xor(ss, 16, 64);
      ss += __shfl_xor(ss, 32, 64);
      l[qf] = l[qf] * scl[qf] + ss;
#pragma unroll
      for (int f = 0; f < 4; ++f)
#pragma unroll
        for (int r = 0; r < 4; ++r) o[qf][f][r] *= scl[qf];
    }

    // ---- P -> bf16 B-operand frags, in-register (cvt_pk + permlane32) ----
    union PW { unsigned u[4]; bf16x8 v; };
    PW pb[2][2];  // [qf][ks]
#pragma unroll
    for (int qf = 0; qf < 2; ++qf) {
      unsigned w[4][2];
#pragma unroll
      for (int kf = 0; kf < 4; ++kf) {
        w[kf][0] = cvtpk(p[qf][kf][0], p[qf][kf][1]);
        w[kf][1] = cvtpk(p[qf][kf][2], p[qf][kf][3]);
      }
#pragma unroll
      for (int ks = 0; ks < 2; ++ks) {
        unsigned a0 = w[2 * ks][0], b0 = w[2 * ks + 1][0];
        unsigned a1 = w[2 * ks][1], b1 = w[2 * ks + 1][1];
        pb[qf][ks].u[0] = hi32 ? b0 : a0;  // in-lane words (j=0..3)
        pb[qf][ks].u[1] = hi32 ? b1 : a1;
        pl32swap(a0, b0);                  // a.hi <-> b.lo
        pl32swap(a1, b1);
        pb[qf][ks].u[2] = hi32 ? a0 : b0;  // cross words (j=4..7)
        pb[qf][ks].u[3] = hi32 ? a1 : b1;
      }
    }

    // ---- O^T += V' P : o[qf][f] ----
    __builtin_amdgcn_s_setprio(1);
#pragma unroll
    for (int ks = 0; ks < 2; ++ks) {
#pragma unroll
      for (int f = 0; f < 4; ++f) {
        const int vrow = (f << 4) + r16;
        const int cb = (ks << 6) + (hf << 4);
        const bf16x8 av = *(const bf16x8*)((const char*)(&Vs[cur][0]) +
                                           vrow * 128 + (cb ^ ((vrow & 7) << 4)));
#pragma unroll
        for (int qf = 0; qf < 2; ++qf)
          o[qf][f] = __builtin_amdgcn_mfma_f32_16x16x32_bf16(av, pb[qf][ks].v,
                                                             o[qf][f], 0, 0, 0);
      }
    }
    __builtin_amdgcn_s_setprio(0);

    __syncthreads();  // drains prefetch + guards buffer reuse
  }
#undef STAGE

  // ---- normalize + write attn_out (B,S,D) bf16 ----
  const int b = bh >> 4, h = bh & 15;
#pragma unroll
  for (int qf = 0; qf < 2; ++qf) {
    const float inv = 1.0f / l[qf];
    const int q = qbase + (qf << 4) + r16;
#pragma unroll
    for (int f = 0; f < 4; ++f)
#pragma unroll
      for (int r = 0; r < 4; ++r) {
        const int dv = (f << 4) + (hf << 2) + r;
        AO[((size_t)b * S + q) * D + (h << 6) + dv] =
            __float2bfloat16(o[qf][f][r] * inv);
      }
  }
}

extern "C" void kernel_launch(void* const* d_in, const int* in_sizes, int n_in,
                              void* d_out, int out_size, void* d_ws, size_t ws_size,
                              hipStream_t stream) {
  (void)in_sizes; (void)n_in; (void)out_size; (void)ws_size;
  const float* x  = (const float*)d_in[0];
  const float* Wq = (const float*)d_in[1];
  const float* Wk = (const float*)d_in[2];
  const float* Wv = (const float*)d_in[3];
  const float* Wo = (const float*)d_in[4];
  float* out = (float*)d_out;
  char* ws = (char*)d_ws;
  const size_t MB = (size_t)1 << 20;
  __hip_bfloat16* xb   = (__hip_bfloat16*)(ws);             //  8 MB
  __hip_bfloat16* Wcat = (__hip_bfloat16*)(ws + 8 * MB);    //  6 MB
  __hip_bfloat16* Wob  = (__hip_bfloat16*)(ws + 14 * MB);   //  2 MB
  __hip_bfloat16* Qr   = (__hip_bfloat16*)(ws + 16 * MB);   //  8 MB (B,H,S,dk)
  __hip_bfloat16* Kr   = (__hip_bfloat16*)(ws + 24 * MB);   //  8 MB
  __hip_bfloat16* Vt   = (__hip_bfloat16*)(ws + 32 * MB);   //  8 MB (B,H,dk,S) k-perm
  __hip_bfloat16* AO   = (__hip_bfloat16*)(ws + 40 * MB);   //  8 MB (B,S,D)
  float* cosT = (float*)(ws + 48 * MB);                     // 256 KB
  float* sinT = (float*)(ws + 48 * MB + 256 * 1024);        // 256 KB

  cvt4_kernel<<<4096, 256, 0, stream>>>(x, xb, (2 * 2048 * 1024) / 4);
  cvt4_kernel<<<1024, 256, 0, stream>>>(Wq, Wcat, (1024 * 1024) / 4);
  cvt4_kernel<<<1024, 256, 0, stream>>>(Wk, Wcat + 1024 * 1024, (1024 * 1024) / 4);
  cvt4_kernel<<<1024, 256, 0, stream>>>(Wv, Wcat + 2 * 1024 * 1024, (1024 * 1024) / 4);
  cvt4_kernel<<<1024, 256, 0, stream>>>(Wo, Wob, (1024 * 1024) / 4);
  rope_tab_kernel<<<(2048 * 32) / 256, 256, 0, stream>>>(cosT, sinT);

  gemm_nt_kernel<1><<<(4096 / 128) * (3072 / 128), 256, 0, stream>>>(
      xb, Wcat, nullptr, Qr, Kr, Vt, cosT, sinT, 3072);
  attn_kernel<<<32 * 16, 256, 0, stream>>>(Qr, Kr, Vt, AO);
  gemm_nt_kernel<0><<<(4096 / 128) * (1024 / 128), 256, 0, stream>>>(
      AO, Wob, out, nullptr, nullptr, nullptr, nullptr, nullptr, 1024);
}

// Round 4
// 221.640 us; speedup vs baseline: 1.2814x; 1.0406x over previous
//
#include <hip/hip_runtime.h>
#include <hip/hip_bf16.h>

typedef float f32x4 __attribute__((ext_vector_type(4)));
typedef __bf16 bf16x8 __attribute__((ext_vector_type(8)));

static constexpr int S  = 2048;
static constexpr int D  = 1024;
static constexpr int DK = 64;
static constexpr int KDIM = 1024;

#define AS1 __attribute__((address_space(1)))
#define AS3 __attribute__((address_space(3)))

__device__ __forceinline__ void glds16(const void* g, void* l) {
  __builtin_amdgcn_global_load_lds((const AS1 void*)g, (AS3 void*)l, 16, 0, 0);
}

__device__ __forceinline__ unsigned cvtpk(float lo, float hi) {
  unsigned r;
  asm("v_cvt_pk_bf16_f32 %0, %1, %2" : "=v"(r) : "v"(lo), "v"(hi));
  return r;
}

__device__ __forceinline__ void pl32swap(unsigned& a, unsigned& b) {
  asm("v_permlane32_swap_b32 %0, %1" : "+v"(a), "+v"(b));
}

// k-permutation within a 64 block (bijective) matching the in-register
// P-transform in attn_kernel.
__device__ __forceinline__ int kperm64(int k) {
  const int kf = k >> 4, hs = (k >> 2) & 3, r = k & 3;
  const bool inl = ((kf & 1) == (hs >> 1));
  const int h = inl ? hs : (hs ^ 2);
  const int j = inl ? r : (r + 4);
  return ((kf >> 1) << 5) + (h << 3) + j;
}

// ---------------- fused pre-pass: all f32->bf16 cvt + RoPE tables ----------
__global__ __launch_bounds__(256) void pre_kernel(
    const float* __restrict__ x,  const float* __restrict__ Wq,
    const float* __restrict__ Wk, const float* __restrict__ Wv,
    const float* __restrict__ Wo,
    __hip_bfloat16* __restrict__ xb, __hip_bfloat16* __restrict__ Wcat,
    __hip_bfloat16* __restrict__ Wob,
    float* __restrict__ cosT, float* __restrict__ sinT) {
  const int gid = blockIdx.x * 256 + threadIdx.x;
  // float4 segments: x 1048576 | Wq/Wk/Wv/Wo 262144 each | rope 65536
  if (gid < 2097152) {
    const float* src;
    __hip_bfloat16* dst;
    int off;
    if (gid < 1048576)      { src = x;  dst = xb;                  off = gid; }
    else if (gid < 1310720) { src = Wq; dst = Wcat;                off = gid - 1048576; }
    else if (gid < 1572864) { src = Wk; dst = Wcat + 1048576;      off = gid - 1310720; }
    else if (gid < 1835008) { src = Wv; dst = Wcat + 2097152;      off = gid - 1572864; }
    else                    { src = Wo; dst = Wob;                 off = gid - 1835008; }
    float4 v = reinterpret_cast<const float4*>(src)[off];
    union { ushort4 u; __hip_bfloat16 h[4]; } o;
    o.h[0] = __float2bfloat16(v.x);
    o.h[1] = __float2bfloat16(v.y);
    o.h[2] = __float2bfloat16(v.z);
    o.h[3] = __float2bfloat16(v.w);
    reinterpret_cast<ushort4*>(dst)[off] = o.u;
  } else {
    const int idx = gid - 2097152;  // S*32
    const int s = idx >> 5, fi = idx & 31;
    float invf = powf(10000.0f, -(float)(2 * fi) / 64.0f);
    float ang = (float)s * invf;
    cosT[idx] = cosf(ang);
    sinT[idx] = sinf(ang);
  }
}

// ---------------- m97-style 128x128x32 NT GEMM (XCD-swizzled) -------------
template <int MODE>
__global__ __launch_bounds__(256) void gemm_nt_kernel(
    const __hip_bfloat16* __restrict__ A,
    const __hip_bfloat16* __restrict__ Bw,
    float* __restrict__ Cf,
    __hip_bfloat16* __restrict__ Qr,
    __hip_bfloat16* __restrict__ Kr,
    __hip_bfloat16* __restrict__ Vt,
    const float* __restrict__ cosT,
    const float* __restrict__ sinT,
    int Ncols) {
  __shared__ __attribute__((aligned(16))) __hip_bfloat16 Asm[128 * 32];
  __shared__ __attribute__((aligned(16))) __hip_bfloat16 Bsm[128 * 32];
  const int tid = threadIdx.x;
  const int nbn = Ncols >> 7;
  // XCD-aware swizzle (grid % 8 == 0 for both call sites)
  const int cpx = gridDim.x >> 3;
  const int swz = (blockIdx.x & 7) * cpx + (blockIdx.x >> 3);
  const int bm = swz / nbn;
  const int bn = swz % nbn;
  const int m0 = bm << 7, n0 = bn << 7;
  const int lane = tid & 63;
  const int wid = tid >> 6;
  const int wm = wid >> 1, wn = wid & 1;
  const int r16 = lane & 15, hf = lane >> 4;

  f32x4 acc[4][4];
#pragma unroll
  for (int i = 0; i < 4; ++i)
#pragma unroll
    for (int j = 0; j < 4; ++j) acc[i][j] = (f32x4)0.0f;

  for (int k0 = 0; k0 < KDIM; k0 += 32) {
    __syncthreads();
#pragma unroll
    for (int i = 0; i < 2; ++i) {
      const int idx = i * 256 + tid;
      const int row = idx >> 2;
      const int cb = (idx & 3) << 4;
      glds16((const char*)A + ((size_t)(m0 + row) * KDIM + k0) * 2 + cb,
             (char*)Asm + idx * 16);
      glds16((const char*)Bw + ((size_t)(n0 + row) * KDIM + k0) * 2 + cb,
             (char*)Bsm + idx * 16);
    }
    __syncthreads();
    bf16x8 af[4], bfr[4];
#pragma unroll
    for (int mi = 0; mi < 4; ++mi)
      af[mi] = *(const bf16x8*)((const char*)Asm +
                                ((wm << 6) + (mi << 4) + r16) * 64 + hf * 16);
#pragma unroll
    for (int ni = 0; ni < 4; ++ni)
      bfr[ni] = *(const bf16x8*)((const char*)Bsm +
                                 ((wn << 6) + (ni << 4) + r16) * 64 + hf * 16);
#pragma unroll
    for (int mi = 0; mi < 4; ++mi)
#pragma unroll
      for (int ni = 0; ni < 4; ++ni)
        acc[mi][ni] = __builtin_amdgcn_mfma_f32_16x16x32_bf16(af[mi], bfr[ni],
                                                              acc[mi][ni], 0, 0, 0);
  }

  if constexpr (MODE == 0) {
#pragma unroll
    for (int mi = 0; mi < 4; ++mi) {
      const int rowb = m0 + (wm << 6) + (mi << 4) + (hf << 2);
#pragma unroll
      for (int ni = 0; ni < 4; ++ni) {
        const int col = n0 + (wn << 6) + (ni << 4) + r16;
#pragma unroll
        for (int r = 0; r < 4; ++r)
          Cf[(size_t)(rowb + r) * Ncols + col] = acc[mi][ni][r];
      }
    }
  } else {
    const int proj = n0 >> 10;
#pragma unroll
    for (int mi = 0; mi < 4; ++mi) {
      const int rowb = m0 + (wm << 6) + (mi << 4) + (hf << 2);
#pragma unroll
      for (int ni = 0; ni < 4; ++ni) {
        const int col = n0 + (wn << 6) + (ni << 4) + r16;
        const int ecol = col & 1023;
        const int h = ecol >> 6, dk = ecol & 63;
#pragma unroll
        for (int r = 0; r < 4; ++r) {
          float v = acc[mi][ni][r];
          const int row = rowb + r;
          const int b = row >> 11, s = row & 2047;
          if (proj < 2) {
            float p = __shfl_xor(v, 1, 64);
            const int fi = dk >> 1;
            const float c = cosT[(s << 5) + fi];
            const float sn = sinT[(s << 5) + fi];
            const float ov = v * c + ((dk & 1) ? p : -p) * sn;
            __hip_bfloat16* dst = (proj == 0) ? Qr : Kr;
            dst[((size_t)((b << 4) + h) * S + s) * DK + dk] = __float2bfloat16(ov);
          } else {
            const int sp = (s & ~63) | kperm64(s & 63);
            Vt[((size_t)((b << 4) + h) * DK + dk) * S + sp] = __float2bfloat16(v);
          }
        }
      }
    }
  }
}

// ---------------- causal flash attention v4 (KV-split, balanced) ----------
// 24 work items per bh: item = 3g+j; j<2 -> split j of qt=15-g (half KV range
// each); j==2 -> whole qt=7-g. Splits write normalized bf16 partials + (m,l).
__global__ __launch_bounds__(256) void attn_kernel(
    const __hip_bfloat16* __restrict__ Q,
    const __hip_bfloat16* __restrict__ Kr,
    const __hip_bfloat16* __restrict__ Vp,
    __hip_bfloat16* __restrict__ AO,
    __hip_bfloat16* __restrict__ Opart,  // [bh][16 splits][128][64] bf16
    float* __restrict__ ml) {            // [bh][16 splits][128][2] f32
  __shared__ __attribute__((aligned(16))) __hip_bfloat16 Ks[2][64 * 64];
  __shared__ __attribute__((aligned(16))) __hip_bfloat16 Vs[2][64 * 64];
  const int tid = threadIdx.x;
  const int lane = tid & 63, wid = tid >> 6;
  const int r16 = lane & 15, hf = lane >> 4;
  const bool hi32 = (lane >= 32);
  const int bh = blockIdx.x & 31;
  const int item = blockIdx.x >> 5;  // 0..23, heavy first
  const int g = item / 3, j = item - 3 * g;
  int qt, k0, k1;
  bool dosplit;
  if (j < 2) {
    qt = 15 - g;
    const int nt = (qt << 1) + 2;
    k0 = j ? (nt >> 1) : 0;
    k1 = j ? nt : (nt >> 1);
    dosplit = true;
  } else {
    qt = 7 - g;
    k0 = 0;
    k1 = (qt << 1) + 2;
    dosplit = false;
  }
  const __hip_bfloat16* Qh = Q + (size_t)bh * S * DK;
  const __hip_bfloat16* Kh = Kr + (size_t)bh * S * DK;
  const __hip_bfloat16* Vh = Vp + (size_t)bh * DK * S;

  const int qbase = (qt << 7) + (wid << 5);

  bf16x8 bq[2][2];
#pragma unroll
  for (int qf = 0; qf < 2; ++qf)
#pragma unroll
    for (int ks = 0; ks < 2; ++ks)
      bq[qf][ks] = *(const bf16x8*)(Qh + (size_t)(qbase + (qf << 4) + r16) * DK +
                                    ks * 32 + hf * 8);

  f32x4 o[2][4];
#pragma unroll
  for (int qf = 0; qf < 2; ++qf)
#pragma unroll
    for (int f = 0; f < 4; ++f) o[qf][f] = (f32x4)0.0f;
  float m[2] = {-1e30f, -1e30f}, l[2] = {0.0f, 0.0f};

#define STAGE(bufi, t)                                                         \
  {                                                                            \
    _Pragma("unroll") for (int i = 0; i < 2; ++i) {                            \
      const int idx = i * 256 + tid;                                           \
      const int row = idx >> 3;                                                \
      const int cb = (idx & 7) << 4;                                           \
      const int scb = cb ^ ((row & 7) << 4);                                   \
      glds16((const char*)Kh + ((size_t)(((t) << 6) + row) * DK) * 2 + scb,    \
             (char*)(&Ks[bufi][0]) + idx * 16);                                \
      glds16((const char*)Vh + ((size_t)row * S + ((t) << 6)) * 2 + scb,       \
             (char*)(&Vs[bufi][0]) + idx * 16);                                \
    }                                                                          \
  }

  STAGE(0, k0);
  __syncthreads();

  for (int kt = k0; kt < k1; ++kt) {
    const int cur = (kt - k0) & 1;
    if (kt + 1 < k1) STAGE(cur ^ 1, kt + 1);

    // S^T = K Q^T
    f32x4 p[2][4];
#pragma unroll
    for (int qf = 0; qf < 2; ++qf)
#pragma unroll
      for (int kf = 0; kf < 4; ++kf) p[qf][kf] = (f32x4)0.0f;
    __builtin_amdgcn_s_setprio(1);
#pragma unroll
    for (int ks = 0; ks < 2; ++ks) {
#pragma unroll
      for (int kf = 0; kf < 4; ++kf) {
        const int krow = (kf << 4) + r16;
        const int cb = (ks << 6) + (hf << 4);
        const bf16x8 ak = *(const bf16x8*)((const char*)(&Ks[cur][0]) +
                                           krow * 128 + (cb ^ ((krow & 7) << 4)));
#pragma unroll
        for (int qf = 0; qf < 2; ++qf)
          p[qf][kf] = __builtin_amdgcn_mfma_f32_16x16x32_bf16(ak, bq[qf][ks],
                                                              p[qf][kf], 0, 0, 0);
      }
    }
    __builtin_amdgcn_s_setprio(0);

    // scale + causal mask
    const bool diag = (kt >= (qt << 1));
#pragma unroll
    for (int qf = 0; qf < 2; ++qf) {
      const int qg = qbase + (qf << 4) + r16;
#pragma unroll
      for (int kf = 0; kf < 4; ++kf)
#pragma unroll
        for (int r = 0; r < 4; ++r) {
          float sv = p[qf][kf][r] * 0.125f;
          if (diag) {
            const int kg = (kt << 6) + (kf << 4) + (hf << 2) + r;
            if (kg > qg) sv = -1e30f;
          }
          p[qf][kf][r] = sv;
        }
    }

    // online softmax (lane-local 16 + 2 shfl)
    float scl[2];
#pragma unroll
    for (int qf = 0; qf < 2; ++qf) {
      float t = p[qf][0][0];
#pragma unroll
      for (int kf = 0; kf < 4; ++kf)
#pragma unroll
        for (int r = 0; r < 4; ++r) t = fmaxf(t, p[qf][kf][r]);
      t = fmaxf(t, __shfl_xor(t, 16, 64));
      t = fmaxf(t, __shfl_xor(t, 32, 64));
      const float mn = fmaxf(m[qf], t);
      scl[qf] = __expf(m[qf] - mn);
      m[qf] = mn;
      float ss = 0.0f;
#pragma unroll
      for (int kf = 0; kf < 4; ++kf)
#pragma unroll
        for (int r = 0; r < 4; ++r) {
          const float e = __expf(p[qf][kf][r] - mn);
          p[qf][kf][r] = e;
          ss += e;
        }
      ss += __shfl_xor(ss, 16, 64);
      ss += __shfl_xor(ss, 32, 64);
      l[qf] = l[qf] * scl[qf] + ss;
#pragma unroll
      for (int f = 0; f < 4; ++f)
#pragma unroll
        for (int r = 0; r < 4; ++r) o[qf][f][r] *= scl[qf];
    }

    // P -> bf16 frags in-register
    union PW { unsigned u[4]; bf16x8 v; };
    PW pb[2][2];
#pragma unroll
    for (int qf = 0; qf < 2; ++qf) {
      unsigned w[4][2];
#pragma unroll
      for (int kf = 0; kf < 4; ++kf) {
        w[kf][0] = cvtpk(p[qf][kf][0], p[qf][kf][1]);
        w[kf][1] = cvtpk(p[qf][kf][2], p[qf][kf][3]);
      }
#pragma unroll
      for (int ks = 0; ks < 2; ++ks) {
        unsigned a0 = w[2 * ks][0], b0 = w[2 * ks + 1][0];
        unsigned a1 = w[2 * ks][1], b1 = w[2 * ks + 1][1];
        pb[qf][ks].u[0] = hi32 ? b0 : a0;
        pb[qf][ks].u[1] = hi32 ? b1 : a1;
        pl32swap(a0, b0);
        pl32swap(a1, b1);
        pb[qf][ks].u[2] = hi32 ? a0 : b0;
        pb[qf][ks].u[3] = hi32 ? a1 : b1;
      }
    }

    // O^T += V' P
    __builtin_amdgcn_s_setprio(1);
#pragma unroll
    for (int ks = 0; ks < 2; ++ks) {
#pragma unroll
      for (int f = 0; f < 4; ++f) {
        const int vrow = (f << 4) + r16;
        const int cb = (ks << 6) + (hf << 4);
        const bf16x8 av = *(const bf16x8*)((const char*)(&Vs[cur][0]) +
                                           vrow * 128 + (cb ^ ((vrow & 7) << 4)));
#pragma unroll
        for (int qf = 0; qf < 2; ++qf)
          o[qf][f] = __builtin_amdgcn_mfma_f32_16x16x32_bf16(av, pb[qf][ks].v,
                                                             o[qf][f], 0, 0, 0);
      }
    }
    __builtin_amdgcn_s_setprio(0);

    __syncthreads();
  }
#undef STAGE

  if (!dosplit) {
    const int b = bh >> 4, h = bh & 15;
#pragma unroll
    for (int qf = 0; qf < 2; ++qf) {
      const float inv = 1.0f / l[qf];
      const int q = qbase + (qf << 4) + r16;
#pragma unroll
      for (int f = 0; f < 4; ++f)
#pragma unroll
        for (int r = 0; r < 4; ++r) {
          const int dv = (f << 4) + (hf << 2) + r;
          AO[((size_t)b * S + q) * D + (h << 6) + dv] =
              __float2bfloat16(o[qf][f][r] * inv);
        }
    }
  } else {
    const int sidx = (g << 1) | j;
    __hip_bfloat16* op = Opart + (((size_t)bh * 16 + sidx) << 13);
    float* mlp = ml + (((size_t)bh * 16 + sidx) << 8);
#pragma unroll
    for (int qf = 0; qf < 2; ++qf) {
      const float inv = 1.0f / l[qf];
      const int rowin = (wid << 5) + (qf << 4) + r16;
#pragma unroll
      for (int f = 0; f < 4; ++f)
#pragma unroll
        for (int r = 0; r < 4; ++r) {
          const int dv = (f << 4) + (hf << 2) + r;
          op[rowin * 64 + dv] = __float2bfloat16(o[qf][f][r] * inv);
        }
      if (hf == 0) {
        mlp[rowin * 2] = m[qf];
        mlp[rowin * 2 + 1] = l[qf];
      }
    }
  }
}

// ---------------- merge the split partials ----------------
__global__ __launch_bounds__(256) void merge_kernel(
    const __hip_bfloat16* __restrict__ Opart,
    const float* __restrict__ ml,
    __hip_bfloat16* __restrict__ AO) {
  const int rg = blockIdx.x * 256 + threadIdx.x;  // 32768 rows
  const int bh = rg >> 10;
  const int rem = rg & 1023;
  const int gq = rem >> 7;         // 0..7 -> qt = 15-gq
  const int rowin = rem & 127;
  const int s0 = bh * 16 + (gq << 1), s1 = s0 + 1;
  const float m0 = ml[(s0 << 8) + rowin * 2], l0 = ml[(s0 << 8) + rowin * 2 + 1];
  const float m1 = ml[(s1 << 8) + rowin * 2], l1 = ml[(s1 << 8) + rowin * 2 + 1];
  const float mx = fmaxf(m0, m1);
  float w0 = l0 * __expf(m0 - mx), w1 = l1 * __expf(m1 - mx);
  const float inv = 1.0f / (w0 + w1);
  w0 *= inv;
  w1 *= inv;
  const bf16x8* p0 = (const bf16x8*)(Opart + (((size_t)s0) << 13) + rowin * 64);
  const bf16x8* p1 = (const bf16x8*)(Opart + (((size_t)s1) << 13) + rowin * 64);
  const int b = bh >> 4, h = bh & 15;
  const int q = ((15 - gq) << 7) + rowin;
  bf16x8* dst = (bf16x8*)(AO + ((size_t)b * S + q) * D + (h << 6));
#pragma unroll
  for (int i = 0; i < 8; ++i) {
    bf16x8 a = p0[i], c = p1[i];
    bf16x8 r;
#pragma unroll
    for (int e = 0; e < 8; ++e)
      r[e] = (__bf16)(w0 * (float)a[e] + w1 * (float)c[e]);
    dst[i] = r;
  }
}

extern "C" void kernel_launch(void* const* d_in, const int* in_sizes, int n_in,
                              void* d_out, int out_size, void* d_ws, size_t ws_size,
                              hipStream_t stream) {
  (void)in_sizes; (void)n_in; (void)out_size; (void)ws_size;
  const float* x  = (const float*)d_in[0];
  const float* Wq = (const float*)d_in[1];
  const float* Wk = (const float*)d_in[2];
  const float* Wv = (const float*)d_in[3];
  const float* Wo = (const float*)d_in[4];
  float* out = (float*)d_out;
  char* ws = (char*)d_ws;
  const size_t MB = (size_t)1 << 20;
  __hip_bfloat16* xb   = (__hip_bfloat16*)(ws);             //  8 MB (dead after gemm1)
  __hip_bfloat16* Wcat = (__hip_bfloat16*)(ws + 8 * MB);    //  6 MB (dead after gemm1)
  __hip_bfloat16* Wob  = (__hip_bfloat16*)(ws + 14 * MB);   //  2 MB (live till gemm0)
  __hip_bfloat16* Qr   = (__hip_bfloat16*)(ws + 16 * MB);   //  8 MB
  __hip_bfloat16* Kr   = (__hip_bfloat16*)(ws + 24 * MB);   //  8 MB
  __hip_bfloat16* Vt   = (__hip_bfloat16*)(ws + 32 * MB);   //  8 MB (k-permuted)
  __hip_bfloat16* AO   = (__hip_bfloat16*)(ws + 40 * MB);   //  8 MB
  float* cosT = (float*)(ws + 48 * MB);                     // 256 KB
  float* sinT = (float*)(ws + 48 * MB + 256 * 1024);        // 256 KB
  // attn partials reuse the xb/Wcat region (dead during attention):
  __hip_bfloat16* Opart = (__hip_bfloat16*)(ws);            //  8 MB
  float* mlbuf = (float*)(ws + 8 * MB);                     //  512 KB

  pre_kernel<<<8448, 256, 0, stream>>>(x, Wq, Wk, Wv, Wo, xb, Wcat, Wob,
                                       cosT, sinT);
  gemm_nt_kernel<1><<<(4096 / 128) * (3072 / 128), 256, 0, stream>>>(
      xb, Wcat, nullptr, Qr, Kr, Vt, cosT, sinT, 3072);
  attn_kernel<<<32 * 24, 256, 0, stream>>>(Qr, Kr, Vt, AO, Opart, mlbuf);
  merge_kernel<<<128, 256, 0, stream>>>(Opart, mlbuf, AO);
  gemm_nt_kernel<0><<<(4096 / 128) * (1024 / 128), 256, 0, stream>>>(
      AO, Wob, out, nullptr, nullptr, nullptr, nullptr, nullptr, 1024);
}

// Round 5
// 217.867 us; speedup vs baseline: 1.3036x; 1.0173x over previous
//
#include <hip/hip_runtime.h>
#include <hip/hip_bf16.h>

typedef float f32x4 __attribute__((ext_vector_type(4)));
typedef __bf16 bf16x8 __attribute__((ext_vector_type(8)));

static constexpr int S  = 2048;
static constexpr int D  = 1024;
static constexpr int DK = 64;
static constexpr int KDIM = 1024;
// 0.125 (1/sqrt(dk)) * log2(e): folded into Q so QK^T lands in exp2 domain
static constexpr float QSCALE = 0.18033688f;

#define AS1 __attribute__((address_space(1)))
#define AS3 __attribute__((address_space(3)))

__device__ __forceinline__ void glds16(const void* g, void* l) {
  __builtin_amdgcn_global_load_lds((const AS1 void*)g, (AS3 void*)l, 16, 0, 0);
}

__device__ __forceinline__ unsigned cvtpk(float lo, float hi) {
  unsigned r;
  asm("v_cvt_pk_bf16_f32 %0, %1, %2" : "=v"(r) : "v"(lo), "v"(hi));
  return r;
}

__device__ __forceinline__ void pl32swap(unsigned& a, unsigned& b) {
  asm("v_permlane32_swap_b32 %0, %1" : "+v"(a), "+v"(b));
}

// 2^x in one instruction
__device__ __forceinline__ float fexp2(float x) {
  float r;
  asm("v_exp_f32 %0, %1" : "=v"(r) : "v"(x));
  return r;
}

// k-permutation within a 64 block (bijective); maps r=0..3 (k aligned 4) to
// consecutive outputs, enabling vectorized V^T stores.
__device__ __forceinline__ int kperm64(int k) {
  const int kf = k >> 4, hs = (k >> 2) & 3, r = k & 3;
  const bool inl = ((kf & 1) == (hs >> 1));
  const int h = inl ? hs : (hs ^ 2);
  const int j = inl ? r : (r + 4);
  return ((kf >> 1) << 5) + (h << 3) + j;
}

// ---------------- fused pre-pass: all f32->bf16 cvt + RoPE tables ----------
__global__ __launch_bounds__(256) void pre_kernel(
    const float* __restrict__ x,  const float* __restrict__ Wq,
    const float* __restrict__ Wk, const float* __restrict__ Wv,
    const float* __restrict__ Wo,
    __hip_bfloat16* __restrict__ xb, __hip_bfloat16* __restrict__ Wcat,
    __hip_bfloat16* __restrict__ Wob,
    float* __restrict__ cosT, float* __restrict__ sinT) {
  const int gid = blockIdx.x * 256 + threadIdx.x;
  if (gid < 2097152) {
    const float* src;
    __hip_bfloat16* dst;
    int off;
    if (gid < 1048576)      { src = x;  dst = xb;             off = gid; }
    else if (gid < 1310720) { src = Wq; dst = Wcat;           off = gid - 1048576; }
    else if (gid < 1572864) { src = Wk; dst = Wcat + 1048576; off = gid - 1310720; }
    else if (gid < 1835008) { src = Wv; dst = Wcat + 2097152; off = gid - 1572864; }
    else                    { src = Wo; dst = Wob;            off = gid - 1835008; }
    float4 v = reinterpret_cast<const float4*>(src)[off];
    union { ushort4 u; __hip_bfloat16 h[4]; } o;
    o.h[0] = __float2bfloat16(v.x);
    o.h[1] = __float2bfloat16(v.y);
    o.h[2] = __float2bfloat16(v.z);
    o.h[3] = __float2bfloat16(v.w);
    reinterpret_cast<ushort4*>(dst)[off] = o.u;
  } else {
    const int idx = gid - 2097152;  // S*32
    const int s = idx >> 5, fi = idx & 31;
    float invf = powf(10000.0f, -(float)(2 * fi) / 64.0f);
    float ang = (float)s * invf;
    cosT[idx] = cosf(ang);
    sinT[idx] = sinf(ang);
  }
}

// ---------------- m97-style 128x128x32 NT GEMM (XCD-swizzled) -------------
template <int MODE>
__global__ __launch_bounds__(256) void gemm_nt_kernel(
    const __hip_bfloat16* __restrict__ A,
    const __hip_bfloat16* __restrict__ Bw,
    float* __restrict__ Cf,
    __hip_bfloat16* __restrict__ Qr,
    __hip_bfloat16* __restrict__ Kr,
    __hip_bfloat16* __restrict__ Vt,
    const float* __restrict__ cosT,
    const float* __restrict__ sinT,
    int Ncols) {
  __shared__ __attribute__((aligned(16))) __hip_bfloat16 Asm[128 * 32];
  __shared__ __attribute__((aligned(16))) __hip_bfloat16 Bsm[128 * 32];
  const int tid = threadIdx.x;
  const int nbn = Ncols >> 7;
  const int cpx = gridDim.x >> 3;
  const int swz = (blockIdx.x & 7) * cpx + (blockIdx.x >> 3);
  const int bm = swz / nbn;
  const int bn = swz % nbn;
  const int m0 = bm << 7, n0 = bn << 7;
  const int lane = tid & 63;
  const int wid = tid >> 6;
  const int wm = wid >> 1, wn = wid & 1;
  const int r16 = lane & 15, hf = lane >> 4;

  f32x4 acc[4][4];
#pragma unroll
  for (int i = 0; i < 4; ++i)
#pragma unroll
    for (int j = 0; j < 4; ++j) acc[i][j] = (f32x4)0.0f;

  for (int k0 = 0; k0 < KDIM; k0 += 32) {
    __syncthreads();
#pragma unroll
    for (int i = 0; i < 2; ++i) {
      const int idx = i * 256 + tid;
      const int row = idx >> 2;
      const int cb = (idx & 3) << 4;
      glds16((const char*)A + ((size_t)(m0 + row) * KDIM + k0) * 2 + cb,
             (char*)Asm + idx * 16);
      glds16((const char*)Bw + ((size_t)(n0 + row) * KDIM + k0) * 2 + cb,
             (char*)Bsm + idx * 16);
    }
    __syncthreads();
    bf16x8 af[4], bfr[4];
#pragma unroll
    for (int mi = 0; mi < 4; ++mi)
      af[mi] = *(const bf16x8*)((const char*)Asm +
                                ((wm << 6) + (mi << 4) + r16) * 64 + hf * 16);
#pragma unroll
    for (int ni = 0; ni < 4; ++ni)
      bfr[ni] = *(const bf16x8*)((const char*)Bsm +
                                 ((wn << 6) + (ni << 4) + r16) * 64 + hf * 16);
#pragma unroll
    for (int mi = 0; mi < 4; ++mi)
#pragma unroll
      for (int ni = 0; ni < 4; ++ni)
        acc[mi][ni] = __builtin_amdgcn_mfma_f32_16x16x32_bf16(af[mi], bfr[ni],
                                                              acc[mi][ni], 0, 0, 0);
  }

  if constexpr (MODE == 0) {
#pragma unroll
    for (int mi = 0; mi < 4; ++mi) {
      const int rowb = m0 + (wm << 6) + (mi << 4) + (hf << 2);
#pragma unroll
      for (int ni = 0; ni < 4; ++ni) {
        const int col = n0 + (wn << 6) + (ni << 4) + r16;
#pragma unroll
        for (int r = 0; r < 4; ++r)
          Cf[(size_t)(rowb + r) * Ncols + col] = acc[mi][ni][r];
      }
    }
  } else {
    const int proj = n0 >> 10;
#pragma unroll
    for (int mi = 0; mi < 4; ++mi) {
      const int rowb = m0 + (wm << 6) + (mi << 4) + (hf << 2);
      const int b = rowb >> 11;          // uniform for r=0..3 (rowb % 4 == 0)
      const int sbase = rowb & 2047;
#pragma unroll
      for (int ni = 0; ni < 4; ++ni) {
        const int col = n0 + (wn << 6) + (ni << 4) + r16;
        const int ecol = col & 1023;
        const int h = ecol >> 6, dk = ecol & 63;
        if (proj < 2) {
#pragma unroll
          for (int r = 0; r < 4; ++r) {
            float v = acc[mi][ni][r];
            const int s = sbase + r;
            float p = __shfl_xor(v, 1, 64);
            const int fi = dk >> 1;
            const float c = cosT[(s << 5) + fi];
            const float sn = sinT[(s << 5) + fi];
            float ov = v * c + ((dk & 1) ? p : -p) * sn;
            if (proj == 0) ov *= QSCALE;  // fold 1/sqrt(dk)*log2e into Q
            __hip_bfloat16* dst = (proj == 0) ? Qr : Kr;
            dst[((size_t)((b << 4) + h) * S + s) * DK + dk] = __float2bfloat16(ov);
          }
        } else {
          // V: k-permuted store; r=0..3 map to consecutive sp -> ushort4
          const int sp0 = (sbase & ~63) | kperm64(sbase & 63);
          union { ushort4 u; __hip_bfloat16 hh[4]; } vp;
#pragma unroll
          for (int r = 0; r < 4; ++r)
            vp.hh[r] = __float2bfloat16(acc[mi][ni][r]);
          *reinterpret_cast<ushort4*>(
              &Vt[((size_t)((b << 4) + h) * DK + dk) * S + sp0]) = vp.u;
        }
      }
    }
  }
}

// ---------------- causal flash attention v5 (balanced triples) ------------
// 24 items/bh (iters: j<2 halves of qt=15-g; j==2 whole qt=7-g). Blocks
// sharing a CU (idx, idx+256, idx+512) get items whose iter counts sum to
// exactly 34 via the triple table.
__global__ __launch_bounds__(256) void attn_kernel(
    const __hip_bfloat16* __restrict__ Q,
    const __hip_bfloat16* __restrict__ Kr,
    const __hip_bfloat16* __restrict__ Vp,
    __hip_bfloat16* __restrict__ AO,
    __hip_bfloat16* __restrict__ Opart,  // [bh][16 splits][128][64] bf16
    float* __restrict__ ml) {            // [bh][16 splits][128][2] f32
  __shared__ __attribute__((aligned(16))) __hip_bfloat16 Ks[2][64 * 64];
  __shared__ __attribute__((aligned(16))) __hip_bfloat16 Vs[2][64 * 64];
  static const int T[8][3] = {{0, 1, 23},  {2, 5, 20},  {3, 9, 17}, {4, 15, 14},
                              {6, 16, 21}, {7, 11, 18}, {10, 8, 22}, {12, 13, 19}};
  const int tid = threadIdx.x;
  const int lane = tid & 63, wid = tid >> 6;
  const int r16 = lane & 15, hf = lane >> 4;
  const bool hi32 = (lane >= 32);
  const int bh = blockIdx.x & 31;
  const int cg = (blockIdx.x >> 5) & 7;
  const int slot = blockIdx.x >> 8;
  const int item = T[cg][slot];
  const int g = item / 3, j = item - 3 * g;
  int qt, k0, k1;
  bool dosplit;
  if (j < 2) {
    qt = 15 - g;
    const int nt = (qt << 1) + 2;
    k0 = j ? (nt >> 1) : 0;
    k1 = j ? nt : (nt >> 1);
    dosplit = true;
  } else {
    qt = 7 - g;
    k0 = 0;
    k1 = (qt << 1) + 2;
    dosplit = false;
  }
  const __hip_bfloat16* Qh = Q + (size_t)bh * S * DK;
  const __hip_bfloat16* Kh = Kr + (size_t)bh * S * DK;
  const __hip_bfloat16* Vh = Vp + (size_t)bh * DK * S;

  const int qbase = (qt << 7) + (wid << 5);

  bf16x8 bq[2][2];
#pragma unroll
  for (int qf = 0; qf < 2; ++qf)
#pragma unroll
    for (int ks = 0; ks < 2; ++ks)
      bq[qf][ks] = *(const bf16x8*)(Qh + (size_t)(qbase + (qf << 4) + r16) * DK +
                                    ks * 32 + hf * 8);

  f32x4 o[2][4];
#pragma unroll
  for (int qf = 0; qf < 2; ++qf)
#pragma unroll
    for (int f = 0; f < 4; ++f) o[qf][f] = (f32x4)0.0f;
  float m[2] = {-1e30f, -1e30f}, l[2] = {0.0f, 0.0f};

#define STAGE(bufi, t)                                                         \
  {                                                                            \
    _Pragma("unroll") for (int i = 0; i < 2; ++i) {                            \
      const int idx = i * 256 + tid;                                           \
      const int row = idx >> 3;                                                \
      const int cb = (idx & 7) << 4;                                           \
      const int scb = cb ^ ((row & 7) << 4);                                   \
      glds16((const char*)Kh + ((size_t)(((t) << 6) + row) * DK) * 2 + scb,    \
             (char*)(&Ks[bufi][0]) + idx * 16);                                \
      glds16((const char*)Vh + ((size_t)row * S + ((t) << 6)) * 2 + scb,       \
             (char*)(&Vs[bufi][0]) + idx * 16);                                \
    }                                                                          \
  }

  STAGE(0, k0);
  __syncthreads();

  for (int kt = k0; kt < k1; ++kt) {
    const int cur = (kt - k0) & 1;
    if (kt + 1 < k1) STAGE(cur ^ 1, kt + 1);

    // S^T = K Q^T  (scores already in exp2 domain via pre-scaled Q)
    f32x4 p[2][4];
#pragma unroll
    for (int qf = 0; qf < 2; ++qf)
#pragma unroll
      for (int kf = 0; kf < 4; ++kf) p[qf][kf] = (f32x4)0.0f;
    __builtin_amdgcn_s_setprio(1);
#pragma unroll
    for (int ks = 0; ks < 2; ++ks) {
#pragma unroll
      for (int kf = 0; kf < 4; ++kf) {
        const int krow = (kf << 4) + r16;
        const int cb = (ks << 6) + (hf << 4);
        const bf16x8 ak = *(const bf16x8*)((const char*)(&Ks[cur][0]) +
                                           krow * 128 + (cb ^ ((krow & 7) << 4)));
#pragma unroll
        for (int qf = 0; qf < 2; ++qf)
          p[qf][kf] = __builtin_amdgcn_mfma_f32_16x16x32_bf16(ak, bq[qf][ks],
                                                              p[qf][kf], 0, 0, 0);
      }
    }
    __builtin_amdgcn_s_setprio(0);

    // causal mask (diag tiles only; wave-uniform branch)
    if (kt >= (qt << 1)) {
#pragma unroll
      for (int qf = 0; qf < 2; ++qf) {
        const int qg = qbase + (qf << 4) + r16;
#pragma unroll
        for (int kf = 0; kf < 4; ++kf)
#pragma unroll
          for (int r = 0; r < 4; ++r) {
            const int kg = (kt << 6) + (kf << 4) + (hf << 2) + r;
            if (kg > qg) p[qf][kf][r] = -1e30f;
          }
      }
    }

    // online softmax with defer-max (T13, THR=8 log2-units)
#pragma unroll
    for (int qf = 0; qf < 2; ++qf) {
      f32x4 m4;
#pragma unroll
      for (int e = 0; e < 4; ++e)
        m4[e] = fmaxf(fmaxf(p[qf][0][e], p[qf][1][e]),
                      fmaxf(p[qf][2][e], p[qf][3][e]));
      float t = fmaxf(fmaxf(m4[0], m4[1]), fmaxf(m4[2], m4[3]));
      t = fmaxf(t, __shfl_xor(t, 16, 64));
      t = fmaxf(t, __shfl_xor(t, 32, 64));
      if (t > m[qf] + 8.0f) {  // wave-uniform
        const float scl = fexp2(m[qf] - t);
        m[qf] = t;
        l[qf] *= scl;
#pragma unroll
        for (int f = 0; f < 4; ++f)
#pragma unroll
          for (int r = 0; r < 4; ++r) o[qf][f][r] *= scl;
      }
      float ss = 0.0f;
#pragma unroll
      for (int kf = 0; kf < 4; ++kf)
#pragma unroll
        for (int r = 0; r < 4; ++r) {
          const float e = fexp2(p[qf][kf][r] - m[qf]);
          p[qf][kf][r] = e;
          ss += e;
        }
      ss += __shfl_xor(ss, 16, 64);
      ss += __shfl_xor(ss, 32, 64);
      l[qf] += ss;
    }

    // P -> bf16 frags in-register
    union PW { unsigned u[4]; bf16x8 v; };
    PW pb[2][2];
#pragma unroll
    for (int qf = 0; qf < 2; ++qf) {
      unsigned w[4][2];
#pragma unroll
      for (int kf = 0; kf < 4; ++kf) {
        w[kf][0] = cvtpk(p[qf][kf][0], p[qf][kf][1]);
        w[kf][1] = cvtpk(p[qf][kf][2], p[qf][kf][3]);
      }
#pragma unroll
      for (int ks = 0; ks < 2; ++ks) {
        unsigned a0 = w[2 * ks][0], b0 = w[2 * ks + 1][0];
        unsigned a1 = w[2 * ks][1], b1 = w[2 * ks + 1][1];
        pb[qf][ks].u[0] = hi32 ? b0 : a0;
        pb[qf][ks].u[1] = hi32 ? b1 : a1;
        pl32swap(a0, b0);
        pl32swap(a1, b1);
        pb[qf][ks].u[2] = hi32 ? a0 : b0;
        pb[qf][ks].u[3] = hi32 ? a1 : b1;
      }
    }

    // O^T += V' P
    __builtin_amdgcn_s_setprio(1);
#pragma unroll
    for (int ks = 0; ks < 2; ++ks) {
#pragma unroll
      for (int f = 0; f < 4; ++f) {
        const int vrow = (f << 4) + r16;
        const int cb = (ks << 6) + (hf << 4);
        const bf16x8 av = *(const bf16x8*)((const char*)(&Vs[cur][0]) +
                                           vrow * 128 + (cb ^ ((vrow & 7) << 4)));
#pragma unroll
        for (int qf = 0; qf < 2; ++qf)
          o[qf][f] = __builtin_amdgcn_mfma_f32_16x16x32_bf16(av, pb[qf][ks].v,
                                                             o[qf][f], 0, 0, 0);
      }
    }
    __builtin_amdgcn_s_setprio(0);

    __syncthreads();
  }
#undef STAGE

  if (!dosplit) {
    const int b = bh >> 4, h = bh & 15;
#pragma unroll
    for (int qf = 0; qf < 2; ++qf) {
      const float inv = 1.0f / l[qf];
      const int q = qbase + (qf << 4) + r16;
#pragma unroll
      for (int f = 0; f < 4; ++f)
#pragma unroll
        for (int r = 0; r < 4; ++r) {
          const int dv = (f << 4) + (hf << 2) + r;
          AO[((size_t)b * S + q) * D + (h << 6) + dv] =
              __float2bfloat16(o[qf][f][r] * inv);
        }
    }
  } else {
    const int sidx = (g << 1) | j;
    __hip_bfloat16* op = Opart + (((size_t)bh * 16 + sidx) << 13);
    float* mlp = ml + (((size_t)bh * 16 + sidx) << 8);
#pragma unroll
    for (int qf = 0; qf < 2; ++qf) {
      const float inv = 1.0f / l[qf];
      const int rowin = (wid << 5) + (qf << 4) + r16;
#pragma unroll
      for (int f = 0; f < 4; ++f)
#pragma unroll
        for (int r = 0; r < 4; ++r) {
          const int dv = (f << 4) + (hf << 2) + r;
          op[rowin * 64 + dv] = __float2bfloat16(o[qf][f][r] * inv);
        }
      if (hf == 0) {
        mlp[rowin * 2] = m[qf];
        mlp[rowin * 2 + 1] = l[qf];
      }
    }
  }
}

// ---------------- merge the split partials (m in exp2 domain) -------------
__global__ __launch_bounds__(256) void merge_kernel(
    const __hip_bfloat16* __restrict__ Opart,
    const float* __restrict__ ml,
    __hip_bfloat16* __restrict__ AO) {
  const int rg = blockIdx.x * 256 + threadIdx.x;  // 32768 rows
  const int bh = rg >> 10;
  const int rem = rg & 1023;
  const int gq = rem >> 7;  // 0..7 -> qt = 15-gq
  const int rowin = rem & 127;
  const int s0 = bh * 16 + (gq << 1), s1 = s0 + 1;
  const float m0 = ml[(s0 << 8) + rowin * 2], l0 = ml[(s0 << 8) + rowin * 2 + 1];
  const float m1 = ml[(s1 << 8) + rowin * 2], l1 = ml[(s1 << 8) + rowin * 2 + 1];
  const float mx = fmaxf(m0, m1);
  float w0 = l0 * fexp2(m0 - mx), w1 = l1 * fexp2(m1 - mx);
  const float inv = 1.0f / (w0 + w1);
  w0 *= inv;
  w1 *= inv;
  const bf16x8* p0 = (const bf16x8*)(Opart + (((size_t)s0) << 13) + rowin * 64);
  const bf16x8* p1 = (const bf16x8*)(Opart + (((size_t)s1) << 13) + rowin * 64);
  const int b = bh >> 4, h = bh & 15;
  const int q = ((15 - gq) << 7) + rowin;
  bf16x8* dst = (bf16x8*)(AO + ((size_t)b * S + q) * D + (h << 6));
#pragma unroll
  for (int i = 0; i < 8; ++i) {
    bf16x8 a = p0[i], c = p1[i];
    bf16x8 r;
#pragma unroll
    for (int e = 0; e < 8; ++e)
      r[e] = (__bf16)(w0 * (float)a[e] + w1 * (float)c[e]);
    dst[i] = r;
  }
}

extern "C" void kernel_launch(void* const* d_in, const int* in_sizes, int n_in,
                              void* d_out, int out_size, void* d_ws, size_t ws_size,
                              hipStream_t stream) {
  (void)in_sizes; (void)n_in; (void)out_size; (void)ws_size;
  const float* x  = (const float*)d_in[0];
  const float* Wq = (const float*)d_in[1];
  const float* Wk = (const float*)d_in[2];
  const float* Wv = (const float*)d_in[3];
  const float* Wo = (const float*)d_in[4];
  float* out = (float*)d_out;
  char* ws = (char*)d_ws;
  const size_t MB = (size_t)1 << 20;
  __hip_bfloat16* xb   = (__hip_bfloat16*)(ws);             //  8 MB (dead after gemm1)
  __hip_bfloat16* Wcat = (__hip_bfloat16*)(ws + 8 * MB);    //  6 MB (dead after gemm1)
  __hip_bfloat16* Wob  = (__hip_bfloat16*)(ws + 14 * MB);   //  2 MB (live till gemm0)
  __hip_bfloat16* Qr   = (__hip_bfloat16*)(ws + 16 * MB);   //  8 MB (pre-scaled)
  __hip_bfloat16* Kr   = (__hip_bfloat16*)(ws + 24 * MB);   //  8 MB
  __hip_bfloat16* Vt   = (__hip_bfloat16*)(ws + 32 * MB);   //  8 MB (k-permuted)
  __hip_bfloat16* AO   = (__hip_bfloat16*)(ws + 40 * MB);   //  8 MB
  float* cosT = (float*)(ws + 48 * MB);                     // 256 KB
  float* sinT = (float*)(ws + 48 * MB + 256 * 1024);        // 256 KB
  __hip_bfloat16* Opart = (__hip_bfloat16*)(ws);            //  8 MB (reuse xb)
  float* mlbuf = (float*)(ws + 8 * MB);                     //  512 KB (reuse Wcat)

  pre_kernel<<<8448, 256, 0, stream>>>(x, Wq, Wk, Wv, Wo, xb, Wcat, Wob,
                                       cosT, sinT);
  gemm_nt_kernel<1><<<(4096 / 128) * (3072 / 128), 256, 0, stream>>>(
      xb, Wcat, nullptr, Qr, Kr, Vt, cosT, sinT, 3072);
  attn_kernel<<<32 * 24, 256, 0, stream>>>(Qr, Kr, Vt, AO, Opart, mlbuf);
  merge_kernel<<<128, 256, 0, stream>>>(Opart, mlbuf, AO);
  gemm_nt_kernel<0><<<(4096 / 128) * (1024 / 128), 256, 0, stream>>>(
      AO, Wob, out, nullptr, nullptr, nullptr, nullptr, nullptr, 1024);
}